// Round 1
// 8991.710 us; speedup vs baseline: 1.2998x; 1.2998x over previous
//
#include <hip/hip_runtime.h>

#define NSTEP 64

typedef short bf8 __attribute__((ext_vector_type(8)));          // 8 x bf16 (4 VGPRs) MFMA A/B frag
typedef float f32x16 __attribute__((ext_vector_type(16)));      // 32x32 MFMA C/D frag
typedef float f32x4 __attribute__((ext_vector_type(4)));
typedef float f32x2 __attribute__((ext_vector_type(2)));
typedef unsigned int u32x4 __attribute__((ext_vector_type(4)));
typedef unsigned int u32x2 __attribute__((ext_vector_type(2)));

static __device__ __forceinline__ float asf(unsigned int u){ return __builtin_bit_cast(float, u); }
static __device__ __forceinline__ unsigned int asu(float f){ return __builtin_bit_cast(unsigned int, f); }

// fp32 pair -> packed bf16 dword (RNE, a in low 16)
#if defined(__has_builtin)
#if __has_builtin(__builtin_amdgcn_cvt_pk_bf16_f32)
#define HAVE_CVT_PK_BF16 1
#endif
#endif
#ifdef HAVE_CVT_PK_BF16
typedef __bf16 bf16x2_t __attribute__((ext_vector_type(2)));
static __device__ __forceinline__ unsigned int pk(float a, float b){
  bf16x2_t r = __builtin_amdgcn_cvt_pk_bf16_f32(a, b);
  return __builtin_bit_cast(unsigned int, r);
}
#else
static __device__ __forceinline__ unsigned int pk(float a, float b){
  unsigned int ua = asu(a); unsigned int ub = asu(b);
  ua += 0x7FFFu + ((ua >> 16) & 1u);
  ub += 0x7FFFu + ((ub >> 16) & 1u);
  return (ua >> 16) | (ub & 0xFFFF0000u);
}
#endif

// bf16 round of a f32 (matches what pk feeds the MFMA)
static __device__ __forceinline__ float bfr(float w){ return asf(pk(w, 0.0f) << 16); }

// packed 2xf32 fma: compiler emits v_pk_fma_f32 on gfx90a+ (scalarizes harmlessly otherwise)
static __device__ __forceinline__ f32x2 pkfma(f32x2 a, f32x2 b, f32x2 c){
  return __builtin_elementwise_fma(a, b, c);
}

static __device__ __forceinline__ f32x2 pairof(const f32x16& v, int j){
  f32x2 r; r.x = v[2*j]; r.y = v[2*j+1]; return r;
}
static __device__ __forceinline__ void setpair(f32x16& v, int j, f32x2 p){
  v[2*j] = p.x; v[2*j+1] = p.y;
}

// half-wave exchange: x.hi(lanes 32-63) <-> y.lo(lanes 0-31), pure VALU (no DS pipe)
static __device__ __forceinline__ void swap32(unsigned int& x, unsigned int& y){
  asm("v_permlane32_swap_b32 %0, %1" : "+v"(x), "+v"(y));
}

// Build standard 32x32x16 B-frag (k = 8*hw + j) from C-layout packed dwords
// p_i = pk(V[2i], V[2i+1]) of one C-layout half V[0..7].
// Derivation: C row map (v&3)+8*(v>>2)+4*hw; swap(p0,p2) makes
//   p0 -> {f0,f1}/{f8,f9} (k=8hw+0,1) and p2 -> {f4,f5}/{f12,f13} (k=8hw+4,5).
// Identical layout to the verified xch2 path (R2-R4), 6 ops vs 12, zero cndmask/DS.
static __device__ __forceinline__ bf8 frag4(unsigned int p0, unsigned int p1,
                                            unsigned int p2v, unsigned int p3v){
  swap32(p0, p2v);
  swap32(p1, p3v);
  u32x4 u; u[0]=p0; u[1]=p1; u[2]=p2v; u[3]=p3v;
  return __builtin_bit_cast(bf8, u);
}

// scale 8 packed bf16 by s (one-time weight prep)
static __device__ __forceinline__ bf8 scale_bf8(bf8 w, float s){
  u32x4 u = __builtin_bit_cast(u32x4, w);
  u32x4 r;
  #pragma unroll
  for(int i=0;i<4;i++){
    float lo = asf(u[i] << 16) * s;
    float hi = asf(u[i] & 0xFFFF0000u) * s;
    r[i] = pk(lo, hi);
  }
  return __builtin_bit_cast(bf8, r);
}

#define MFMA32 __builtin_amdgcn_mfma_f32_32x32x16_bf16

// Shifted ELU: GEMM1 gives q = p*log2e (weights pre-scaled).
// h' = h+1 = max(q,0)*ln2 + exp2(min(q,0)).  4 VALU ops/elem (pkfma packs the fma).
// The +1 shift is compensated in b2' = b2 - rowsum(bf16(W2)).
#define ELUPACK(QT, P) \
  _Pragma("unroll") \
  for(int j=0;j<8;j++){ \
    f32x2 q = pairof(QT, j); \
    f32x2 m; m.x = fmaxf(q.x, 0.0f); m.y = fmaxf(q.y, 0.0f); \
    f32x2 e; e.x = __builtin_amdgcn_exp2f(fminf(q.x, 0.0f)); \
             e.y = __builtin_amdgcn_exp2f(fminf(q.y, 0.0f)); \
    f32x2 h = pkfma(m, LN22, e); \
    P[j] = pk(h.x, h.y); \
  }

// Block = 128 threads = 2 waves sharing one 32-row batch group.
// Wave wv owns hidden [wv*128, wv*128+128). Partial k summed across the pair via LDS
// (static parity double-buffer, 1 barrier/stage).
__global__ __launch_bounds__(128, 1) void ode_kernel(
    const void* __restrict__ xv,
    const void* __restrict__ tv,
    const void* __restrict__ W1v,
    const void* __restrict__ b1v,
    const void* __restrict__ W2v,
    const void* __restrict__ b2v,
    void* __restrict__ outv)
{
  __shared__ __align__(16) float b1s[256];
  __shared__ __align__(16) float b2s[64];
  __shared__ __align__(16) float xbuf[2][2][2048];   // [parity][wave][8 chunks * 64 lanes * 4 dw]

  const int tid = threadIdx.x;     // 0..127
  const int lid = tid & 63;        // lane in wave
  const int wv  = tid >> 6;        // wave in pair: hidden-half owner

  // ---- runtime input-dtype detection (wave-uniform; both waves identical) ----
  const unsigned int* w1u = (const unsigned int*)W1v;
  bool bad = false;
  #pragma unroll
  for(int i=0; i<2; i++){
    unsigned int d = w1u[i*64 + lid];
    unsigned int e0 = (d >> 7)  & 0xFFu;
    unsigned int e1 = (d >> 23) & 0xFFu;
    bad |= (e0 >= 125u) || (e1 >= 125u);
  }
  const bool f32in = (__ballot(bad) != 0ull);

  const float L2E = 1.4426950408889634f;

  // ---- biases to LDS: b1' = b1*log2e ; b2' = (b2 - rowsum(bf16 W2)) * 0.5 ----
  if(f32in){
    #pragma unroll
    for(int i=0; i<2; i++) b1s[tid + i*128] = ((const float*)b1v)[tid + i*128] * L2E;
  } else {
    #pragma unroll
    for(int i=0; i<2; i++)
      b1s[tid + i*128] = asf((unsigned int)((const unsigned short*)b1v)[tid + i*128] << 16) * L2E;
  }
  if(tid < 64){
    float ssum = 0.0f;
    if(f32in){
      const float* W2 = (const float*)W2v + tid*256;
      #pragma unroll 4
      for(int k=0; k<64; k++){
        f32x4 w4 = *(const f32x4*)(W2 + k*4);
        ssum += bfr(w4[0]) + bfr(w4[1]) + bfr(w4[2]) + bfr(w4[3]);
      }
    } else {
      const unsigned short* W2 = (const unsigned short*)W2v + tid*256;
      for(int k=0; k<256; k++) ssum += asf((unsigned int)W2[k] << 16);
    }
    float bb = f32in ? ((const float*)b2v)[tid]
                     : asf((unsigned int)((const unsigned short*)b2v)[tid] << 16);
    b2s[tid] = (bb - ssum) * 0.5f;   // both waves seed with half
  }
  __syncthreads();

  const int ln = lid & 31;         // MFMA n-index = batch row within group
  const int hw = (lid >> 5) & 1;   // half-wave select
  const int r  = blockIdx.x * 32 + ln;   // global batch row

  const float t  = f32in ? ((const float*)tv)[0]
                         : asf((unsigned int)((const unsigned short*)tv)[0] << 16);
  const float dt  = t / (float)NSTEP;
  const float hdt = 0.5f * dt;
  const float g   = dt * (1.0f/6.0f);
  const f32x2 DT2  = {dt, dt};
  const f32x2 HDT2 = {hdt, hdt};
  const f32x2 TWO2 = {2.0f, 2.0f};
  const f32x2 G2   = {g, g};
  const f32x2 LN22 = {0.6931471805599453f, 0.6931471805599453f};

  // ---- weight A-fragments (this wave's hidden half only); W1 pre-scaled by log2e ----
  bf8 W1f[4][4];   // [mtl: hidden tile within half][kt over 64 input feats]
  bf8 W2f[2][8];   // [f_out tile][ktl over this half's 128 hidden]
  if(f32in){
    const float* W1 = (const float*)W1v;
    const float* W2 = (const float*)W2v;
    #pragma unroll
    for(int mtl=0; mtl<4; mtl++){
      #pragma unroll
      for(int kt=0; kt<4; kt++){
        const float* p = W1 + (wv*128 + mtl*32 + ln)*64 + kt*16 + hw*8;
        f32x4 a = *(const f32x4*)p;
        f32x4 b = *(const f32x4*)(p + 4);
        u32x4 u;
        u[0]=pk(a[0]*L2E, a[1]*L2E); u[1]=pk(a[2]*L2E, a[3]*L2E);
        u[2]=pk(b[0]*L2E, b[1]*L2E); u[3]=pk(b[2]*L2E, b[3]*L2E);
        W1f[mtl][kt] = __builtin_bit_cast(bf8, u);
      }
    }
    #pragma unroll
    for(int mt=0; mt<2; mt++){
      #pragma unroll
      for(int ktl=0; ktl<8; ktl++){
        const float* p = W2 + (mt*32 + ln)*256 + wv*128 + ktl*16 + hw*8;
        f32x4 a = *(const f32x4*)p;
        f32x4 b = *(const f32x4*)(p + 4);
        u32x4 u; u[0]=pk(a[0],a[1]); u[1]=pk(a[2],a[3]); u[2]=pk(b[0],b[1]); u[3]=pk(b[2],b[3]);
        W2f[mt][ktl] = __builtin_bit_cast(bf8, u);
      }
    }
  } else {
    const unsigned short* W1 = (const unsigned short*)W1v;
    const unsigned short* W2 = (const unsigned short*)W2v;
    #pragma unroll
    for(int mtl=0; mtl<4; mtl++)
      #pragma unroll
      for(int kt=0; kt<4; kt++)
        W1f[mtl][kt] = scale_bf8(*(const bf8*)(W1 + (wv*128 + mtl*32 + ln)*64 + kt*16 + hw*8), L2E);
    #pragma unroll
    for(int mt=0; mt<2; mt++)
      #pragma unroll
      for(int ktl=0; ktl<8; ktl++)
        W2f[mt][ktl] = *(const bf8*)(W2 + (mt*32 + ln)*256 + wv*128 + ktl*16 + hw*8);
  }

  // ---- state Y in C-layout: element 4q+i of Y{mt} = y[r][32mt + 8q + 4hw + i] ----
  f32x16 Y0, Y1;
  if(f32in){
    const float* x = (const float*)xv;
    #pragma unroll
    for(int q=0; q<4; q++){
      f32x4 v0 = *(const f32x4*)(x + r*64 +      q*8 + hw*4);
      f32x4 v1 = *(const f32x4*)(x + r*64 + 32 + q*8 + hw*4);
      #pragma unroll
      for(int i=0;i<4;i++){ Y0[4*q+i] = v0[i]; Y1[4*q+i] = v1[i]; }
    }
  } else {
    const unsigned short* x = (const unsigned short*)xv;
    #pragma unroll
    for(int q=0; q<4; q++){
      u32x2 v0 = *(const u32x2*)(x + r*64 +      q*8 + hw*4);
      u32x2 v1 = *(const u32x2*)(x + r*64 + 32 + q*8 + hw*4);
      Y0[4*q+0]=asf(v0[0]<<16); Y0[4*q+1]=asf(v0[0]&0xFFFF0000u);
      Y0[4*q+2]=asf(v0[1]<<16); Y0[4*q+3]=asf(v0[1]&0xFFFF0000u);
      Y1[4*q+0]=asf(v1[0]<<16); Y1[4*q+1]=asf(v1[0]&0xFFFF0000u);
      Y1[4*q+2]=asf(v1[1]<<16); Y1[4*q+3]=asf(v1[1]&0xFFFF0000u);
    }
  }

  f32x16 c20, c21;   // full k of previous stage (post-exchange)
  #pragma unroll
  for(int i=0;i<16;i++){ c20[i]=0.0f; c21[i]=0.0f; }

  // One chunk of 64 hidden units (chunk CH local to this wave's half):
  // GEMM1 -> shifted-ELU -> permlane-frag -> GEMM2 partial
  #define CHUNK(CH) { \
    f32x16 a10, a11; \
    _Pragma("unroll") \
    for(int q=0; q<4; q++){ \
      f32x4 t0 = *(const f32x4*)&b1s[wv*128 + CH*64 +      q*8 + hw*4]; \
      f32x4 t1 = *(const f32x4*)&b1s[wv*128 + CH*64 + 32 + q*8 + hw*4]; \
      _Pragma("unroll") \
      for(int i=0;i<4;i++){ a10[4*q+i] = t0[i]; a11[4*q+i] = t1[i]; } \
    } \
    a10 = MFMA32(W1f[CH*2+0][0], zf0, a10, 0,0,0); \
    a10 = MFMA32(W1f[CH*2+0][1], zf1, a10, 0,0,0); \
    a10 = MFMA32(W1f[CH*2+0][2], zf2, a10, 0,0,0); \
    a10 = MFMA32(W1f[CH*2+0][3], zf3, a10, 0,0,0); \
    a11 = MFMA32(W1f[CH*2+1][0], zf0, a11, 0,0,0); \
    a11 = MFMA32(W1f[CH*2+1][1], zf1, a11, 0,0,0); \
    a11 = MFMA32(W1f[CH*2+1][2], zf2, a11, 0,0,0); \
    a11 = MFMA32(W1f[CH*2+1][3], zf3, a11, 0,0,0); \
    unsigned int P0[8], P1[8]; \
    ELUPACK(a10, P0) \
    ELUPACK(a11, P1) \
    bf8 hf0 = frag4(P0[0], P0[1], P0[2], P0[3]); \
    bf8 hf1 = frag4(P0[4], P0[5], P0[6], P0[7]); \
    bf8 hf2 = frag4(P1[0], P1[1], P1[2], P1[3]); \
    bf8 hf3 = frag4(P1[4], P1[5], P1[6], P1[7]); \
    p20 = MFMA32(W2f[0][CH*4+0], hf0, p20, 0,0,0); \
    p20 = MFMA32(W2f[0][CH*4+1], hf1, p20, 0,0,0); \
    p20 = MFMA32(W2f[0][CH*4+2], hf2, p20, 0,0,0); \
    p20 = MFMA32(W2f[0][CH*4+3], hf3, p20, 0,0,0); \
    p21 = MFMA32(W2f[1][CH*4+0], hf0, p21, 0,0,0); \
    p21 = MFMA32(W2f[1][CH*4+1], hf1, p21, 0,0,0); \
    p21 = MFMA32(W2f[1][CH*4+2], hf2, p21, 0,0,0); \
    p21 = MFMA32(W2f[1][CH*4+3], hf3, p21, 0,0,0); \
  }

  #pragma unroll 1
  for(int step=0; step<NSTEP; step++){
    f32x16 A0, A1;   // RK4 accumulator: s0 writes it fully (A = k1)

    #pragma unroll
    for(int s=0; s<4; s++){
      // z = Y + c*K  (s==0: z = Y) -> bf16 pack -> B-frags for GEMM1
      unsigned int Z0[8], Z1[8];
      #pragma unroll
      for(int j=0;j<8;j++){
        f32x2 z0, z1;
        if(s == 0){ z0 = pairof(Y0,j); z1 = pairof(Y1,j); }
        else {
          const f32x2 cc = (s==3) ? DT2 : HDT2;
          z0 = pkfma(cc, pairof(c20,j), pairof(Y0,j));
          z1 = pkfma(cc, pairof(c21,j), pairof(Y1,j));
        }
        Z0[j] = pk(z0.x, z0.y);
        Z1[j] = pk(z1.x, z1.y);
      }
      bf8 zf0 = frag4(Z0[0], Z0[1], Z0[2], Z0[3]);
      bf8 zf1 = frag4(Z0[4], Z0[5], Z0[6], Z0[7]);
      bf8 zf2 = frag4(Z1[0], Z1[1], Z1[2], Z1[3]);
      bf8 zf3 = frag4(Z1[4], Z1[5], Z1[6], Z1[7]);

      // partial-k accumulator: both waves seed with b2'/2 (uniform, no branch)
      f32x16 p20, p21;
      #pragma unroll
      for(int q=0; q<4; q++){
        f32x4 t0 = *(const f32x4*)&b2s[     q*8 + hw*4];
        f32x4 t1 = *(const f32x4*)&b2s[32 + q*8 + hw*4];
        #pragma unroll
        for(int i=0;i<4;i++){ p20[4*q+i] = t0[i]; p21[4*q+i] = t1[i]; }
      }

      CHUNK(0)
      CHUNK(1)

      // ---- sum partials across the wave pair via LDS (parity = s&1, 1 barrier) ----
      {
        const int sb = s & 1;
        float* my = &xbuf[sb][wv][0];
        #pragma unroll
        for(int cc=0; cc<4; cc++){
          f32x4 v0, v1;
          #pragma unroll
          for(int i=0;i<4;i++){ v0[i] = p20[4*cc+i]; v1[i] = p21[4*cc+i]; }
          *(f32x4*)&my[(cc*64 + lid)*4]       = v0;
          *(f32x4*)&my[((cc+4)*64 + lid)*4]   = v1;
        }
        __syncthreads();
        const float* pr = &xbuf[sb][1-wv][0];
        #pragma unroll
        for(int cc=0; cc<4; cc++){
          f32x4 v0 = *(const f32x4*)&pr[(cc*64 + lid)*4];
          f32x4 v1 = *(const f32x4*)&pr[((cc+4)*64 + lid)*4];
          f32x2 a, b;
          a.x=v0[0]; a.y=v0[1]; b.x=v0[2]; b.y=v0[3];
          setpair(c20, 2*cc,   pairof(p20, 2*cc)   + a);
          setpair(c20, 2*cc+1, pairof(p20, 2*cc+1) + b);
          a.x=v1[0]; a.y=v1[1]; b.x=v1[2]; b.y=v1[3];
          setpair(c21, 2*cc,   pairof(p21, 2*cc)   + a);
          setpair(c21, 2*cc+1, pairof(p21, 2*cc+1) + b);
        }
      }

      // RK accumulate: s0: A = k1; s1,s2: A += 2k; s3: A += k4
      #pragma unroll
      for(int j=0;j<8;j++){
        if(s == 0){
          setpair(A0, j, pairof(c20, j));
          setpair(A1, j, pairof(c21, j));
        } else if(s == 3){
          setpair(A0, j, pairof(A0, j) + pairof(c20, j));
          setpair(A1, j, pairof(A1, j) + pairof(c21, j));
        } else {
          setpair(A0, j, pkfma(TWO2, pairof(c20, j), pairof(A0, j)));
          setpair(A1, j, pkfma(TWO2, pairof(c21, j), pairof(A1, j)));
        }
      }
    }

    // Y += dt/6 * A
    #pragma unroll
    for(int j=0;j<8;j++){
      setpair(Y0, j, pkfma(G2, pairof(A0, j), pairof(Y0, j)));
      setpair(Y1, j, pkfma(G2, pairof(A1, j), pairof(Y1, j)));
    }
  }

  // ---- store y (wave 0 only; both waves hold identical Y) ----
  if(wv == 0){
    if(f32in){
      float* out = (float*)outv;
      #pragma unroll
      for(int q=0; q<4; q++){
        f32x4 v0, v1;
        #pragma unroll
        for(int i=0;i<4;i++){ v0[i] = Y0[4*q+i]; v1[i] = Y1[4*q+i]; }
        *(f32x4*)(out + r*64 +      q*8 + hw*4) = v0;
        *(f32x4*)(out + r*64 + 32 + q*8 + hw*4) = v1;
      }
    } else {
      unsigned short* out = (unsigned short*)outv;
      #pragma unroll
      for(int q=0; q<4; q++){
        u32x2 v0, v1;
        v0[0] = pk(Y0[4*q+0], Y0[4*q+1]);
        v0[1] = pk(Y0[4*q+2], Y0[4*q+3]);
        v1[0] = pk(Y1[4*q+0], Y1[4*q+1]);
        v1[1] = pk(Y1[4*q+2], Y1[4*q+3]);
        *(u32x2*)(out + r*64 +      q*8 + hw*4) = v0;
        *(u32x2*)(out + r*64 + 32 + q*8 + hw*4) = v1;
      }
    }
  }
}

extern "C" void kernel_launch(void* const* d_in, const int* in_sizes, int n_in,
                              void* d_out, int out_size, void* d_ws, size_t ws_size,
                              hipStream_t stream){
  // 262144 rows / 32 rows per pair, 1 pair (128 threads) per block = 8192 blocks
  hipLaunchKernelGGL(ode_kernel, dim3(8192), dim3(128), 0, stream,
                     d_in[0], d_in[1], d_in[2], d_in[3], d_in[4], d_in[5], d_out);
}

// Round 2
// 7616.198 us; speedup vs baseline: 1.5346x; 1.1806x over previous
//
#include <hip/hip_runtime.h>

#define NSTEP 64

typedef short bf8 __attribute__((ext_vector_type(8)));          // 8 x bf16 (4 VGPRs) MFMA A/B frag
typedef float f32x16 __attribute__((ext_vector_type(16)));
typedef float f32x4 __attribute__((ext_vector_type(4)));        // 16x16 MFMA C/D frag
typedef float f32x2 __attribute__((ext_vector_type(2)));
typedef unsigned int u32x4 __attribute__((ext_vector_type(4)));
typedef unsigned int u32x2 __attribute__((ext_vector_type(2)));

static __device__ __forceinline__ float asf(unsigned int u){ return __builtin_bit_cast(float, u); }
static __device__ __forceinline__ unsigned int asu(float f){ return __builtin_bit_cast(unsigned int, f); }

// fp32 pair -> packed bf16 dword (RNE, a in low 16)
#if defined(__has_builtin)
#if __has_builtin(__builtin_amdgcn_cvt_pk_bf16_f32)
#define HAVE_CVT_PK_BF16 1
#endif
#endif
#ifdef HAVE_CVT_PK_BF16
typedef __bf16 bf16x2_t __attribute__((ext_vector_type(2)));
static __device__ __forceinline__ unsigned int pk(float a, float b){
  bf16x2_t r = __builtin_amdgcn_cvt_pk_bf16_f32(a, b);
  return __builtin_bit_cast(unsigned int, r);
}
#else
static __device__ __forceinline__ unsigned int pk(float a, float b){
  unsigned int ua = asu(a); unsigned int ub = asu(b);
  ua += 0x7FFFu + ((ua >> 16) & 1u);
  ub += 0x7FFFu + ((ub >> 16) & 1u);
  return (ua >> 16) | (ub & 0xFFFF0000u);
}
#endif

// bf16 round of a f32 (matches what pk feeds the MFMA)
static __device__ __forceinline__ float bfr(float w){ return asf(pk(w, 0.0f) << 16); }

// packed 2xf32 math: compiler emits v_pk_* on gfx90a+
static __device__ __forceinline__ f32x2 pkfma(f32x2 a, f32x2 b, f32x2 c){
  return __builtin_elementwise_fma(a, b, c);
}

static __device__ __forceinline__ f32x2 pairof(const f32x16& v, int j){
  f32x2 r; r.x = v[2*j]; r.y = v[2*j+1]; return r;
}
static __device__ __forceinline__ void setpair(f32x16& v, int j, f32x2 p){
  v[2*j] = p.x; v[2*j+1] = p.y;
}

// cross-lane swaps (pure VALU, no DS pipe)
static __device__ __forceinline__ void swap32(unsigned int& x, unsigned int& y){
  asm("v_permlane32_swap_b32 %0, %1" : "+v"(x), "+v"(y));
}
static __device__ __forceinline__ void swap16(unsigned int& x, unsigned int& y){
  asm("v_permlane16_swap_b32 %0, %1" : "+v"(x), "+v"(y));
}

// Build 16x16x32 B-frag (k = 8*(lane>>4)+j, n = lane&15) from C-layout packed dwords
// of a pair of adjacent 16-row tiles (row = (lane>>4)*4 + reg, col = lane&15).
// p0d = pk(tile0 elems 2d,2d+1), p1d = pk(tile1 elems 2d,2d+1).
// swap32 then swap16 on (p00,p10) yields B-dwords 0 and 2; (p01,p11) -> 1 and 3.
// (element-wise verified against m89 C layout + standard B layout)
static __device__ __forceinline__ bf8 mkfrag(unsigned int p00, unsigned int p01,
                                             unsigned int p10, unsigned int p11){
  swap32(p00, p10); swap16(p00, p10);   // p00 = B0, p10 = B2
  swap32(p01, p11); swap16(p01, p11);   // p01 = B1, p11 = B3
  u32x4 u; u[0]=p00; u[1]=p01; u[2]=p10; u[3]=p11;
  return __builtin_bit_cast(bf8, u);
}

// scale 8 packed bf16 by s (one-time weight prep)
static __device__ __forceinline__ bf8 scale_bf8(bf8 w, float s){
  u32x4 u = __builtin_bit_cast(u32x4, w);
  u32x4 r;
  #pragma unroll
  for(int i=0;i<4;i++){
    float lo = asf(u[i] << 16) * s;
    float hi = asf(u[i] & 0xFFFF0000u) * s;
    r[i] = pk(lo, hi);
  }
  return __builtin_bit_cast(bf8, r);
}

#define MFMA16 __builtin_amdgcn_mfma_f32_16x16x32_bf16

// Shifted ELU on a 16x16 C-frag (4 elems): GEMM1 gives q = p*log2e (weights pre-scaled).
// h' = h+1 = max(q,0)*ln2 + exp2(min(q,0)); +1 shift compensated in b2' = b2 - rowsum(bf16 W2).
#define ELU2(A, H0, H1) { \
  f32x2 q0; q0.x=A[0]; q0.y=A[1]; \
  f32x2 q1; q1.x=A[2]; q1.y=A[3]; \
  f32x2 m0 = __builtin_elementwise_max(q0, Z2); \
  f32x2 n0 = __builtin_elementwise_min(q0, Z2); \
  f32x2 m1 = __builtin_elementwise_max(q1, Z2); \
  f32x2 n1 = __builtin_elementwise_min(q1, Z2); \
  f32x2 e0; e0.x=__builtin_amdgcn_exp2f(n0.x); e0.y=__builtin_amdgcn_exp2f(n0.y); \
  f32x2 e1; e1.x=__builtin_amdgcn_exp2f(n1.x); e1.y=__builtin_amdgcn_exp2f(n1.y); \
  f32x2 h0 = pkfma(m0, LN22, e0); \
  f32x2 h1 = pkfma(m1, LN22, e1); \
  H0 = pk(h0.x, h0.y); H1 = pk(h1.x, h1.y); \
}

// Block = 128 threads = 2 waves sharing one 16-row batch group (16x16x32 MFMA).
// Wave wv owns hidden [wv*128, wv*128+128). Partial k summed across the pair via LDS
// (parity double-buffer, 1 barrier/stage). Total regs ~240 -> 2 waves/SIMD.
__global__ __launch_bounds__(128, 2) void ode_kernel(
    const void* __restrict__ xv,
    const void* __restrict__ tv,
    const void* __restrict__ W1v,
    const void* __restrict__ b1v,
    const void* __restrict__ W2v,
    const void* __restrict__ b2v,
    void* __restrict__ outv)
{
  __shared__ __align__(16) float b1s[256];
  __shared__ __align__(16) float b2s[64];
  __shared__ __align__(16) float xbuf[2][2][1024];   // [parity][wave][4 tiles * 64 lanes * 4 dw]

  const int tid = threadIdx.x;     // 0..127
  const int lid = tid & 63;        // lane in wave
  const int wv  = tid >> 6;        // wave in pair: hidden-half owner

  // ---- runtime input-dtype detection (wave-uniform; both waves identical) ----
  const unsigned int* w1u = (const unsigned int*)W1v;
  bool bad = false;
  #pragma unroll
  for(int i=0; i<2; i++){
    unsigned int d = w1u[i*64 + lid];
    unsigned int e0 = (d >> 7)  & 0xFFu;
    unsigned int e1 = (d >> 23) & 0xFFu;
    bad |= (e0 >= 125u) || (e1 >= 125u);
  }
  const bool f32in = (__ballot(bad) != 0ull);

  const float L2E = 1.4426950408889634f;

  // ---- biases to LDS: b1' = b1*log2e ; b2' = (b2 - rowsum(bf16 W2)) * 0.5 ----
  if(f32in){
    #pragma unroll
    for(int i=0; i<2; i++) b1s[tid + i*128] = ((const float*)b1v)[tid + i*128] * L2E;
  } else {
    #pragma unroll
    for(int i=0; i<2; i++)
      b1s[tid + i*128] = asf((unsigned int)((const unsigned short*)b1v)[tid + i*128] << 16) * L2E;
  }
  if(tid < 64){
    float ssum = 0.0f;
    if(f32in){
      const float* W2 = (const float*)W2v + tid*256;
      #pragma unroll 4
      for(int k=0; k<64; k++){
        f32x4 w4 = *(const f32x4*)(W2 + k*4);
        ssum += bfr(w4[0]) + bfr(w4[1]) + bfr(w4[2]) + bfr(w4[3]);
      }
    } else {
      const unsigned short* W2 = (const unsigned short*)W2v + tid*256;
      for(int k=0; k<256; k++) ssum += asf((unsigned int)W2[k] << 16);
    }
    float bb = f32in ? ((const float*)b2v)[tid]
                     : asf((unsigned int)((const unsigned short*)b2v)[tid] << 16);
    b2s[tid] = (bb - ssum) * 0.5f;   // both waves seed with half
  }
  __syncthreads();

  const int ln = lid & 15;         // MFMA m/n index = batch row within group
  const int g  = lid >> 4;         // lane group 0..3 (k-group / C row group)
  const int g4 = g * 4;
  const int rr = blockIdx.x * 16 + ln;   // global batch row

  const float t  = f32in ? ((const float*)tv)[0]
                         : asf((unsigned int)((const unsigned short*)tv)[0] << 16);
  const float dt  = t / (float)NSTEP;
  const float hdt = 0.5f * dt;
  const float gg  = dt * (1.0f/6.0f);
  const f32x2 DT2  = {dt, dt};
  const f32x2 HDT2 = {hdt, hdt};
  const f32x2 TWO2 = {2.0f, 2.0f};
  const f32x2 G2   = {gg, gg};
  const f32x2 LN22 = {0.6931471805599453f, 0.6931471805599453f};
  const f32x2 Z2   = {0.0f, 0.0f};

  // ---- weight A-fragments; A[m = lane&15][k = 8*(lane>>4)+j]; W1 pre-scaled by log2e ----
  bf8 W1f[8][2];   // [mtl: 16-row hidden tile within this wave's 128][ks: two 32-feat k-steps]
  bf8 W2f[4][4];   // [mt: 16-row out tile][kt: four 32-hidden k-steps of this wave's half]
  if(f32in){
    const float* W1 = (const float*)W1v;
    const float* W2 = (const float*)W2v;
    #pragma unroll
    for(int mtl=0; mtl<8; mtl++){
      #pragma unroll
      for(int ks=0; ks<2; ks++){
        const float* p = W1 + (wv*128 + mtl*16 + ln)*64 + ks*32 + g*8;
        f32x4 a = *(const f32x4*)p;
        f32x4 b = *(const f32x4*)(p + 4);
        u32x4 u;
        u[0]=pk(a[0]*L2E, a[1]*L2E); u[1]=pk(a[2]*L2E, a[3]*L2E);
        u[2]=pk(b[0]*L2E, b[1]*L2E); u[3]=pk(b[2]*L2E, b[3]*L2E);
        W1f[mtl][ks] = __builtin_bit_cast(bf8, u);
      }
    }
    #pragma unroll
    for(int mt=0; mt<4; mt++){
      #pragma unroll
      for(int kt=0; kt<4; kt++){
        const float* p = W2 + (mt*16 + ln)*256 + wv*128 + kt*32 + g*8;
        f32x4 a = *(const f32x4*)p;
        f32x4 b = *(const f32x4*)(p + 4);
        u32x4 u; u[0]=pk(a[0],a[1]); u[1]=pk(a[2],a[3]); u[2]=pk(b[0],b[1]); u[3]=pk(b[2],b[3]);
        W2f[mt][kt] = __builtin_bit_cast(bf8, u);
      }
    }
  } else {
    const unsigned short* W1 = (const unsigned short*)W1v;
    const unsigned short* W2 = (const unsigned short*)W2v;
    #pragma unroll
    for(int mtl=0; mtl<8; mtl++)
      #pragma unroll
      for(int ks=0; ks<2; ks++)
        W1f[mtl][ks] = scale_bf8(*(const bf8*)(W1 + (wv*128 + mtl*16 + ln)*64 + ks*32 + g*8), L2E);
    #pragma unroll
    for(int mt=0; mt<4; mt++)
      #pragma unroll
      for(int kt=0; kt<4; kt++)
        W2f[mt][kt] = *(const bf8*)(W2 + (mt*16 + ln)*256 + wv*128 + kt*32 + g*8);
  }

  // ---- state Y in 16x16 C-layout: Y[4*mt+i] = y[rr][mt*16 + g*4 + i], mt=0..3 ----
  f32x16 Y;
  if(f32in){
    const float* x = (const float*)xv;
    #pragma unroll
    for(int mt=0; mt<4; mt++){
      f32x4 v = *(const f32x4*)(x + rr*64 + mt*16 + g4);
      #pragma unroll
      for(int i=0;i<4;i++) Y[4*mt+i] = v[i];
    }
  } else {
    const unsigned short* x = (const unsigned short*)xv;
    #pragma unroll
    for(int mt=0; mt<4; mt++){
      u32x2 v = *(const u32x2*)(x + rr*64 + mt*16 + g4);
      Y[4*mt+0]=asf(v[0]<<16); Y[4*mt+1]=asf(v[0]&0xFFFF0000u);
      Y[4*mt+2]=asf(v[1]<<16); Y[4*mt+3]=asf(v[1]&0xFFFF0000u);
    }
  }

  f32x16 c2;   // full k of previous stage (post-exchange)
  #pragma unroll
  for(int i=0;i<16;i++) c2[i]=0.0f;

  // One chunk = 32 hidden units (GEMM1 tile pair 2KT,2KT+1 -> ELU -> frag -> GEMM2 k-step KT)
  #define CHUNK(KT) { \
    f32x4 a0 = *(const f32x4*)&b1s[wv*128 + (2*KT)*16 + g4]; \
    f32x4 a1 = *(const f32x4*)&b1s[wv*128 + (2*KT+1)*16 + g4]; \
    a0 = MFMA16(W1f[2*KT  ][0], zf0, a0, 0,0,0); \
    a0 = MFMA16(W1f[2*KT  ][1], zf1, a0, 0,0,0); \
    a1 = MFMA16(W1f[2*KT+1][0], zf0, a1, 0,0,0); \
    a1 = MFMA16(W1f[2*KT+1][1], zf1, a1, 0,0,0); \
    unsigned int H00,H01,H10,H11; \
    ELU2(a0, H00, H01) \
    ELU2(a1, H10, H11) \
    bf8 hf = mkfrag(H00, H01, H10, H11); \
    p2[0] = MFMA16(W2f[0][KT], hf, p2[0], 0,0,0); \
    p2[1] = MFMA16(W2f[1][KT], hf, p2[1], 0,0,0); \
    p2[2] = MFMA16(W2f[2][KT], hf, p2[2], 0,0,0); \
    p2[3] = MFMA16(W2f[3][KT], hf, p2[3], 0,0,0); \
  }

  int par = 0;

  #pragma unroll 1
  for(int step=0; step<NSTEP; step++){
    f32x16 A;   // RK4 accumulator: s0 writes it fully (A = k1)

    #pragma unroll
    for(int s=0; s<4; s++){
      // z = Y + c*K  (s==0: z = Y) -> bf16 pack -> 2 B-frags for GEMM1
      unsigned int P[4][2];
      #pragma unroll
      for(int mt=0; mt<4; mt++){
        #pragma unroll
        for(int d=0; d<2; d++){
          f32x2 z;
          if(s == 0){ z = pairof(Y, 2*mt+d); }
          else {
            const f32x2 cc = (s==3) ? DT2 : HDT2;
            z = pkfma(cc, pairof(c2, 2*mt+d), pairof(Y, 2*mt+d));
          }
          P[mt][d] = pk(z.x, z.y);
        }
      }
      bf8 zf0 = mkfrag(P[0][0], P[0][1], P[1][0], P[1][1]);   // feats  0..31
      bf8 zf1 = mkfrag(P[2][0], P[2][1], P[3][0], P[3][1]);   // feats 32..63

      // partial-k accumulators seeded with b2'/2 (uniform across waves)
      f32x4 p2[4];
      #pragma unroll
      for(int mt=0; mt<4; mt++) p2[mt] = *(const f32x4*)&b2s[mt*16 + g4];

      CHUNK(0) CHUNK(1) CHUNK(2) CHUNK(3)

      // ---- sum partials across the wave pair via LDS (parity buffer, 1 barrier) ----
      {
        float* my = &xbuf[par][wv][0];
        #pragma unroll
        for(int mt=0; mt<4; mt++)
          *(f32x4*)&my[(mt*64 + lid)*4] = p2[mt];
        __syncthreads();
        const float* prr = &xbuf[par][1-wv][0];
        #pragma unroll
        for(int mt=0; mt<4; mt++){
          f32x4 v = *(const f32x4*)&prr[(mt*64 + lid)*4];
          f32x2 s0; s0.x = p2[mt][0]+v[0]; s0.y = p2[mt][1]+v[1];
          f32x2 s1; s1.x = p2[mt][2]+v[2]; s1.y = p2[mt][3]+v[3];
          setpair(c2, 2*mt,   s0);
          setpair(c2, 2*mt+1, s1);
        }
        par ^= 1;
      }

      // RK accumulate: s0: A = k1; s1,s2: A += 2k; s3: A += k4
      #pragma unroll
      for(int j=0;j<8;j++){
        if(s == 0)      setpair(A, j, pairof(c2, j));
        else if(s == 3) setpair(A, j, pairof(A, j) + pairof(c2, j));
        else            setpair(A, j, pkfma(TWO2, pairof(c2, j), pairof(A, j)));
      }
    }

    // Y += dt/6 * A
    #pragma unroll
    for(int j=0;j<8;j++)
      setpair(Y, j, pkfma(G2, pairof(A, j), pairof(Y, j)));
  }

  // ---- store y (wave 0 only; both waves hold identical Y) ----
  if(wv == 0){
    if(f32in){
      float* out = (float*)outv;
      #pragma unroll
      for(int mt=0; mt<4; mt++){
        f32x4 v;
        #pragma unroll
        for(int i=0;i<4;i++) v[i] = Y[4*mt+i];
        *(f32x4*)(out + rr*64 + mt*16 + g4) = v;
      }
    } else {
      unsigned short* out = (unsigned short*)outv;
      #pragma unroll
      for(int mt=0; mt<4; mt++){
        u32x2 v;
        v[0] = pk(Y[4*mt+0], Y[4*mt+1]);
        v[1] = pk(Y[4*mt+2], Y[4*mt+3]);
        *(u32x2*)(out + rr*64 + mt*16 + g4) = v;
      }
    }
  }
}

extern "C" void kernel_launch(void* const* d_in, const int* in_sizes, int n_in,
                              void* d_out, int out_size, void* d_ws, size_t ws_size,
                              hipStream_t stream){
  // 262144 rows / 16 rows per pair, 1 pair (128 threads) per block = 16384 blocks
  hipLaunchKernelGGL(ode_kernel, dim3(16384), dim3(128), 0, stream,
                     d_in[0], d_in[1], d_in[2], d_in[3], d_in[4], d_in[5], d_out);
}

// Round 3
// 7138.078 us; speedup vs baseline: 1.6373x; 1.0670x over previous
//
#include <hip/hip_runtime.h>

#define NSTEP 64

typedef short bf8 __attribute__((ext_vector_type(8)));          // 8 x bf16 (4 VGPRs) MFMA A/B frag
typedef float f32x16 __attribute__((ext_vector_type(16)));
typedef float f32x4 __attribute__((ext_vector_type(4)));        // 16x16 MFMA C/D frag
typedef float f32x2 __attribute__((ext_vector_type(2)));
typedef unsigned int u32x4 __attribute__((ext_vector_type(4)));
typedef unsigned int u32x2 __attribute__((ext_vector_type(2)));

static __device__ __forceinline__ float asf(unsigned int u){ return __builtin_bit_cast(float, u); }
static __device__ __forceinline__ unsigned int asu(float f){ return __builtin_bit_cast(unsigned int, f); }

// fp32 pair -> packed bf16 dword (RNE, a in low 16)
#if defined(__has_builtin)
#if __has_builtin(__builtin_amdgcn_cvt_pk_bf16_f32)
#define HAVE_CVT_PK_BF16 1
#endif
#endif
#ifdef HAVE_CVT_PK_BF16
typedef __bf16 bf16x2_t __attribute__((ext_vector_type(2)));
static __device__ __forceinline__ unsigned int pk(float a, float b){
  bf16x2_t r = __builtin_amdgcn_cvt_pk_bf16_f32(a, b);
  return __builtin_bit_cast(unsigned int, r);
}
#else
static __device__ __forceinline__ unsigned int pk(float a, float b){
  unsigned int ua = asu(a); unsigned int ub = asu(b);
  ua += 0x7FFFu + ((ua >> 16) & 1u);
  ub += 0x7FFFu + ((ub >> 16) & 1u);
  return (ua >> 16) | (ub & 0xFFFF0000u);
}
#endif

// bf16 round of a f32 (matches what pk feeds the MFMA)
static __device__ __forceinline__ float bfr(float w){ return asf(pk(w, 0.0f) << 16); }

// packed 2xf32 math: compiler emits v_pk_* on gfx90a+
static __device__ __forceinline__ f32x2 pkfma(f32x2 a, f32x2 b, f32x2 c){
  return __builtin_elementwise_fma(a, b, c);
}

static __device__ __forceinline__ f32x2 pairof(const f32x16& v, int j){
  f32x2 r; r.x = v[2*j]; r.y = v[2*j+1]; return r;
}
static __device__ __forceinline__ void setpair(f32x16& v, int j, f32x2 p){
  v[2*j] = p.x; v[2*j+1] = p.y;
}

// scale 8 packed bf16 by s (one-time weight prep)
static __device__ __forceinline__ bf8 scale_bf8(bf8 w, float s){
  u32x4 u = __builtin_bit_cast(u32x4, w);
  u32x4 r;
  #pragma unroll
  for(int i=0;i<4;i++){
    float lo = asf(u[i] << 16) * s;
    float hi = asf(u[i] & 0xFFFF0000u) * s;
    r[i] = pk(lo, hi);
  }
  return __builtin_bit_cast(bf8, r);
}

#define MFMA16 __builtin_amdgcn_mfma_f32_16x16x32_bf16

// ---- k-permuted fragments: ZERO cross-lane ops ----------------------------
// MFMA contracts fixed slots (lane-group g, reg j). Applying the SAME bijection
// pi(g,j)->k to A and B leaves the result unchanged. We pick
//   j<4 : k = t0_base + 4g + j        (tile t0's C-frag elems 0..3)
//   j>=4: k = t1_base + 4g + (j-4)    (tile t1's C-frag elems 0..3)
// so the B-frag is exactly {pk(v0,v1),pk(v2,v3)} of tile t0 followed by tile t1
// -- the natural post-GEMM C-layout, no permlane swaps. Weights (A-side) are
// loaded with the matching column permutation (two 8B loads per frag).

// Shifted ELU on a 16x16 C-frag (4 elems): GEMM1 gives q = p*log2e (weights pre-scaled).
// h' = h+1 = max(q,0)*ln2 + exp2(min(q,0)); +1 shift compensated in b2' = b2 - rowsum(bf16 W2).
#define ELU2(A, H0, H1) { \
  f32x2 q0; q0.x=A[0]; q0.y=A[1]; \
  f32x2 q1; q1.x=A[2]; q1.y=A[3]; \
  f32x2 m0 = __builtin_elementwise_max(q0, Z2); \
  f32x2 n0 = __builtin_elementwise_min(q0, Z2); \
  f32x2 m1 = __builtin_elementwise_max(q1, Z2); \
  f32x2 n1 = __builtin_elementwise_min(q1, Z2); \
  f32x2 e0; e0.x=__builtin_amdgcn_exp2f(n0.x); e0.y=__builtin_amdgcn_exp2f(n0.y); \
  f32x2 e1; e1.x=__builtin_amdgcn_exp2f(n1.x); e1.y=__builtin_amdgcn_exp2f(n1.y); \
  f32x2 h0 = pkfma(m0, LN22, e0); \
  f32x2 h1 = pkfma(m1, LN22, e1); \
  H0 = pk(h0.x, h0.y); H1 = pk(h1.x, h1.y); \
}

// Block = 128 threads = 2 waves sharing one 16-row batch group (16x16x32 MFMA).
// Wave wv owns hidden [wv*128, wv*128+128). Partial k summed across the pair via LDS
// (parity double-buffer, 1 barrier/stage). ~2 waves/SIMD.
__global__ __launch_bounds__(128, 2) void ode_kernel(
    const void* __restrict__ xv,
    const void* __restrict__ tv,
    const void* __restrict__ W1v,
    const void* __restrict__ b1v,
    const void* __restrict__ W2v,
    const void* __restrict__ b2v,
    void* __restrict__ outv)
{
  __shared__ __align__(16) float b1s[256];
  __shared__ __align__(16) float b2s[64];
  __shared__ __align__(16) float xbuf[2][2][1024];   // [parity][wave][4 tiles * 64 lanes * 4 dw]

  const int tid = threadIdx.x;     // 0..127
  const int lid = tid & 63;        // lane in wave
  const int wv  = tid >> 6;        // wave in pair: hidden-half owner

  // ---- runtime input-dtype detection (wave-uniform; both waves identical) ----
  const unsigned int* w1u = (const unsigned int*)W1v;
  bool bad = false;
  #pragma unroll
  for(int i=0; i<2; i++){
    unsigned int d = w1u[i*64 + lid];
    unsigned int e0 = (d >> 7)  & 0xFFu;
    unsigned int e1 = (d >> 23) & 0xFFu;
    bad |= (e0 >= 125u) || (e1 >= 125u);
  }
  const bool f32in = (__ballot(bad) != 0ull);

  const float L2E = 1.4426950408889634f;

  // ---- biases to LDS: b1' = b1*log2e ; b2' = (b2 - rowsum(bf16 W2)) * 0.5 ----
  if(f32in){
    #pragma unroll
    for(int i=0; i<2; i++) b1s[tid + i*128] = ((const float*)b1v)[tid + i*128] * L2E;
  } else {
    #pragma unroll
    for(int i=0; i<2; i++)
      b1s[tid + i*128] = asf((unsigned int)((const unsigned short*)b1v)[tid + i*128] << 16) * L2E;
  }
  if(tid < 64){
    float ssum = 0.0f;
    if(f32in){
      const float* W2 = (const float*)W2v + tid*256;
      #pragma unroll 4
      for(int k=0; k<64; k++){
        f32x4 w4 = *(const f32x4*)(W2 + k*4);
        ssum += bfr(w4[0]) + bfr(w4[1]) + bfr(w4[2]) + bfr(w4[3]);
      }
    } else {
      const unsigned short* W2 = (const unsigned short*)W2v + tid*256;
      for(int k=0; k<256; k++) ssum += asf((unsigned int)W2[k] << 16);
    }
    float bb = f32in ? ((const float*)b2v)[tid]
                     : asf((unsigned int)((const unsigned short*)b2v)[tid] << 16);
    b2s[tid] = (bb - ssum) * 0.5f;   // both waves seed with half
  }
  __syncthreads();

  const int ln = lid & 15;         // MFMA m/n index = batch row within group
  const int g  = lid >> 4;         // lane group 0..3 (k-group / C row group)
  const int g4 = g * 4;
  const int rr = blockIdx.x * 16 + ln;   // global batch row

  const float t  = f32in ? ((const float*)tv)[0]
                         : asf((unsigned int)((const unsigned short*)tv)[0] << 16);
  const float dt  = t / (float)NSTEP;
  const float hdt = 0.5f * dt;
  const float gg  = dt * (1.0f/6.0f);
  const f32x2 DT2  = {dt, dt};
  const f32x2 HDT2 = {hdt, hdt};
  const f32x2 TWO2 = {2.0f, 2.0f};
  const f32x2 G2   = {gg, gg};
  const f32x2 LN22 = {0.6931471805599453f, 0.6931471805599453f};
  const f32x2 Z2   = {0.0f, 0.0f};

  // ---- weight A-fragments with the k-permutation (j<4 -> base+4g+j, j>=4 -> base+16+4g+j-4);
  //      W1 pre-scaled by log2e ----
  bf8 W1f[8][2];   // [mtl: 16-row hidden tile within this wave's 128][ks: two 32-feat k-steps]
  bf8 W2f[4][4];   // [mt: 16-row out tile][kt: four 32-hidden k-steps of this wave's half]
  if(f32in){
    const float* W1 = (const float*)W1v;
    const float* W2 = (const float*)W2v;
    #pragma unroll
    for(int mtl=0; mtl<8; mtl++){
      #pragma unroll
      for(int ks=0; ks<2; ks++){
        const float* p = W1 + (wv*128 + mtl*16 + ln)*64 + ks*32 + g4;
        f32x4 a = *(const f32x4*)p;          // feats base+4g..+3   (slots j=0..3)
        f32x4 b = *(const f32x4*)(p + 16);   // feats base+16+4g..  (slots j=4..7)
        u32x4 u;
        u[0]=pk(a[0]*L2E, a[1]*L2E); u[1]=pk(a[2]*L2E, a[3]*L2E);
        u[2]=pk(b[0]*L2E, b[1]*L2E); u[3]=pk(b[2]*L2E, b[3]*L2E);
        W1f[mtl][ks] = __builtin_bit_cast(bf8, u);
      }
    }
    #pragma unroll
    for(int mt=0; mt<4; mt++){
      #pragma unroll
      for(int kt=0; kt<4; kt++){
        const float* p = W2 + (mt*16 + ln)*256 + wv*128 + kt*32 + g4;
        f32x4 a = *(const f32x4*)p;
        f32x4 b = *(const f32x4*)(p + 16);
        u32x4 u; u[0]=pk(a[0],a[1]); u[1]=pk(a[2],a[3]); u[2]=pk(b[0],b[1]); u[3]=pk(b[2],b[3]);
        W2f[mt][kt] = __builtin_bit_cast(bf8, u);
      }
    }
  } else {
    const unsigned short* W1 = (const unsigned short*)W1v;
    const unsigned short* W2 = (const unsigned short*)W2v;
    #pragma unroll
    for(int mtl=0; mtl<8; mtl++){
      #pragma unroll
      for(int ks=0; ks<2; ks++){
        const unsigned short* p = W1 + (wv*128 + mtl*16 + ln)*64 + ks*32 + g4;
        u32x2 lo = *(const u32x2*)p;         // feats base+4g..+3
        u32x2 hi = *(const u32x2*)(p + 16);  // feats base+16+4g..
        u32x4 u; u[0]=lo[0]; u[1]=lo[1]; u[2]=hi[0]; u[3]=hi[1];
        W1f[mtl][ks] = scale_bf8(__builtin_bit_cast(bf8, u), L2E);
      }
    }
    #pragma unroll
    for(int mt=0; mt<4; mt++){
      #pragma unroll
      for(int kt=0; kt<4; kt++){
        const unsigned short* p = W2 + (mt*16 + ln)*256 + wv*128 + kt*32 + g4;
        u32x2 lo = *(const u32x2*)p;
        u32x2 hi = *(const u32x2*)(p + 16);
        u32x4 u; u[0]=lo[0]; u[1]=lo[1]; u[2]=hi[0]; u[3]=hi[1];
        W2f[mt][kt] = __builtin_bit_cast(bf8, u);
      }
    }
  }

  // ---- state Y in 16x16 C-layout: Y[4*mt+i] = y[rr][mt*16 + g*4 + i], mt=0..3 ----
  f32x16 Y;
  if(f32in){
    const float* x = (const float*)xv;
    #pragma unroll
    for(int mt=0; mt<4; mt++){
      f32x4 v = *(const f32x4*)(x + rr*64 + mt*16 + g4);
      #pragma unroll
      for(int i=0;i<4;i++) Y[4*mt+i] = v[i];
    }
  } else {
    const unsigned short* x = (const unsigned short*)xv;
    #pragma unroll
    for(int mt=0; mt<4; mt++){
      u32x2 v = *(const u32x2*)(x + rr*64 + mt*16 + g4);
      Y[4*mt+0]=asf(v[0]<<16); Y[4*mt+1]=asf(v[0]&0xFFFF0000u);
      Y[4*mt+2]=asf(v[1]<<16); Y[4*mt+3]=asf(v[1]&0xFFFF0000u);
    }
  }

  f32x16 c2;   // full k of previous stage (post-exchange)
  #pragma unroll
  for(int i=0;i<16;i++) c2[i]=0.0f;

  // One chunk = 32 hidden units (GEMM1 tile pair 2KT,2KT+1 -> ELU -> pack -> GEMM2 k-step KT).
  // hf assembled directly from ELU output dwords (k-permuted frag, no cross-lane).
  #define CHUNK(KT) { \
    f32x4 a0 = *(const f32x4*)&b1s[wv*128 + (2*KT)*16 + g4]; \
    f32x4 a1 = *(const f32x4*)&b1s[wv*128 + (2*KT+1)*16 + g4]; \
    a0 = MFMA16(W1f[2*KT  ][0], zf0, a0, 0,0,0); \
    a0 = MFMA16(W1f[2*KT  ][1], zf1, a0, 0,0,0); \
    a1 = MFMA16(W1f[2*KT+1][0], zf0, a1, 0,0,0); \
    a1 = MFMA16(W1f[2*KT+1][1], zf1, a1, 0,0,0); \
    unsigned int H00,H01,H10,H11; \
    ELU2(a0, H00, H01) \
    ELU2(a1, H10, H11) \
    u32x4 hu; hu[0]=H00; hu[1]=H01; hu[2]=H10; hu[3]=H11; \
    bf8 hf = __builtin_bit_cast(bf8, hu); \
    p2[0] = MFMA16(W2f[0][KT], hf, p2[0], 0,0,0); \
    p2[1] = MFMA16(W2f[1][KT], hf, p2[1], 0,0,0); \
    p2[2] = MFMA16(W2f[2][KT], hf, p2[2], 0,0,0); \
    p2[3] = MFMA16(W2f[3][KT], hf, p2[3], 0,0,0); \
  }

  int par = 0;

  #pragma unroll 1
  for(int step=0; step<NSTEP; step++){
    f32x16 A;   // RK4 accumulator: s0 writes it fully (A = k1)

    #pragma unroll
    for(int s=0; s<4; s++){
      // z = Y + c*K  (s==0: z = Y) -> bf16 pack -> 2 B-frags (k-permuted, pack only)
      unsigned int P[8];
      #pragma unroll
      for(int j=0; j<8; j++){
        f32x2 z;
        if(s == 0){ z = pairof(Y, j); }
        else {
          const f32x2 cc = (s==3) ? DT2 : HDT2;
          z = pkfma(cc, pairof(c2, j), pairof(Y, j));
        }
        P[j] = pk(z.x, z.y);
      }
      u32x4 z0u; z0u[0]=P[0]; z0u[1]=P[1]; z0u[2]=P[2]; z0u[3]=P[3];
      u32x4 z1u; z1u[0]=P[4]; z1u[1]=P[5]; z1u[2]=P[6]; z1u[3]=P[7];
      bf8 zf0 = __builtin_bit_cast(bf8, z0u);   // feats  0..31 (tiles 0,1)
      bf8 zf1 = __builtin_bit_cast(bf8, z1u);   // feats 32..63 (tiles 2,3)

      // partial-k accumulators seeded with b2'/2 (uniform across waves)
      f32x4 p2[4];
      #pragma unroll
      for(int mt=0; mt<4; mt++) p2[mt] = *(const f32x4*)&b2s[mt*16 + g4];

      CHUNK(0) CHUNK(1) CHUNK(2) CHUNK(3)

      // ---- sum partials across the wave pair via LDS (parity buffer, 1 barrier) ----
      {
        float* my = &xbuf[par][wv][0];
        #pragma unroll
        for(int mt=0; mt<4; mt++)
          *(f32x4*)&my[(mt*64 + lid)*4] = p2[mt];
        __syncthreads();
        const float* prr = &xbuf[par][1-wv][0];
        #pragma unroll
        for(int mt=0; mt<4; mt++){
          f32x4 v = *(const f32x4*)&prr[(mt*64 + lid)*4];
          f32x2 s0; s0.x = p2[mt][0]+v[0]; s0.y = p2[mt][1]+v[1];
          f32x2 s1; s1.x = p2[mt][2]+v[2]; s1.y = p2[mt][3]+v[3];
          setpair(c2, 2*mt,   s0);
          setpair(c2, 2*mt+1, s1);
        }
        par ^= 1;
      }

      // RK accumulate: s0: A = k1; s1,s2: A += 2k; s3: A += k4
      #pragma unroll
      for(int j=0;j<8;j++){
        if(s == 0)      setpair(A, j, pairof(c2, j));
        else if(s == 3) setpair(A, j, pairof(A, j) + pairof(c2, j));
        else            setpair(A, j, pkfma(TWO2, pairof(c2, j), pairof(A, j)));
      }
    }

    // Y += dt/6 * A
    #pragma unroll
    for(int j=0;j<8;j++)
      setpair(Y, j, pkfma(G2, pairof(A, j), pairof(Y, j)));
  }

  // ---- store y (wave 0 only; both waves hold identical Y) ----
  if(wv == 0){
    if(f32in){
      float* out = (float*)outv;
      #pragma unroll
      for(int mt=0; mt<4; mt++){
        f32x4 v;
        #pragma unroll
        for(int i=0;i<4;i++) v[i] = Y[4*mt+i];
        *(f32x4*)(out + rr*64 + mt*16 + g4) = v;
      }
    } else {
      unsigned short* out = (unsigned short*)outv;
      #pragma unroll
      for(int mt=0; mt<4; mt++){
        u32x2 v;
        v[0] = pk(Y[4*mt+0], Y[4*mt+1]);
        v[1] = pk(Y[4*mt+2], Y[4*mt+3]);
        *(u32x2*)(out + rr*64 + mt*16 + g4) = v;
      }
    }
  }
}

extern "C" void kernel_launch(void* const* d_in, const int* in_sizes, int n_in,
                              void* d_out, int out_size, void* d_ws, size_t ws_size,
                              hipStream_t stream){
  // 262144 rows / 16 rows per pair, 1 pair (128 threads) per block = 16384 blocks
  hipLaunchKernelGGL(ode_kernel, dim3(16384), dim3(128), 0, stream,
                     d_in[0], d_in[1], d_in[2], d_in[3], d_in[4], d_in[5], d_out);
}